// Round 7
// baseline (837.355 us; speedup 1.0000x reference)
//
#include <hip/hip_runtime.h>
#include <hip/hip_bf16.h>
#include <hip/hip_cooperative_groups.h>

namespace cg = cooperative_groups;

// ---------------------------------------------------------------------------
// HINormer forward, single cooperative megakernel (R7).
// Phases (grid.sync between):
//  P0 wt transpose->bf16 + zero ecnt
//  P1 fc tiles (MFMA) + degree count (atomics)
//  P2 scan1   P3 scan2   P4 scan3 (col_ptr/cursor/dis)
//  per layer l: gemm tiles (+ CSR fill when l==0) | gather (full / ego)
//  P9 pred
// Rationale: R6 showed all kernels <43us; ~120us of the 260us total was
// inter-kernel launch gaps across 14 dispatches. One kernel, 9 grid syncs.
// ---------------------------------------------------------------------------

typedef __attribute__((ext_vector_type(8))) short short8;   // 8 bf16
typedef __attribute__((ext_vector_type(4))) float f32x4;
typedef unsigned short u16;

__device__ __forceinline__ float bf2f(u16 u) {
  union { float f; unsigned int i; } v; v.i = (unsigned int)u << 16; return v.f;
}
__device__ __forceinline__ u16 f2bf(float f) {
  union { float f; unsigned int i; } v; v.f = f;
  return (u16)((v.i + 0x7FFF + ((v.i >> 16) & 1)) >> 16);
}

#define NPB 128
#define SWZ(row, byte) ((byte) ^ (((row) & 15) << 4))

struct MegaParams {
  const float* x; const int* label; const int* seqs;
  const int* row; const int* col; const int* ntype;
  const float* fcW; const float* fcB; const float* gcnW; const float* gcnB;
  const float* predW; const float* predB;
  u16* gh; u16* xws; u16* gh2; u16* wt;
  float* dis; int* ecnt; int* scanex; int* col_ptr; int* cursor; int* partial;
  int* edge_row;
  float* out_logits; float* out_label;
  int n, e, T, L, C, slen, b_total;
};

// stage a [128 x 128] bf16 tile (row stride 128) into swizzled LDS; rows >=
// rows_valid zero-filled. 256 threads: 2 threads/row, 128B each.
__device__ __forceinline__ void stage_tile_bf16(char* smem, const u16* gsrc,
                                                int rows_valid, int t) {
  int row = t >> 1;
  int h = (t & 1) * 64;
  int byte0 = row * 256 + h * 2;
  if (row < rows_valid) {
    const u16* src = gsrc + (size_t)row * 128 + h;
#pragma unroll
    for (int j = 0; j < 8; ++j) {
      short8 v = *(const short8*)(src + j * 8);
      *(short8*)(smem + SWZ(row, byte0 + j * 16)) = v;
    }
  } else {
    short8 z = (short8){0, 0, 0, 0, 0, 0, 0, 0};
#pragma unroll
    for (int j = 0; j < 8; ++j)
      *(short8*)(smem + SWZ(row, byte0 + j * 16)) = z;
  }
}

// 4 waves; wave w covers output cols [w*32, w*32+32). B preloaded (32 VGPR),
// A streamed from LDS: per k-slice 8 ds_read_b128 : 16 MFMA.
__device__ __forceinline__ void mfma_core128(const char* xs, const char* wt, int t,
                                             f32x4 acc[8][2]) {
  const int lane = t & 63, w = t >> 6;
  const int lr = lane & 15, lk = lane >> 4;
  short8 bfrag[4][2];
#pragma unroll
  for (int ks = 0; ks < 4; ++ks) {
    int kb = ks * 64 + lk * 16;
#pragma unroll
    for (int ch = 0; ch < 2; ++ch) {
      int row = w * 32 + ch * 16 + lr;
      bfrag[ks][ch] = *(const short8*)(wt + SWZ(row, row * 256 + kb));
    }
  }
#pragma unroll
  for (int ks = 0; ks < 4; ++ks) {
    int kb = ks * 64 + lk * 16;
    short8 a[8];
#pragma unroll
    for (int rg = 0; rg < 8; ++rg) {
      int row = rg * 16 + lr;
      a[rg] = *(const short8*)(xs + SWZ(row, row * 256 + kb));
    }
#pragma unroll
    for (int rg = 0; rg < 8; ++rg)
#pragma unroll
      for (int ch = 0; ch < 2; ++ch)
        acc[rg][ch] = __builtin_amdgcn_mfma_f32_16x16x32_bf16(a[rg], bfrag[ks][ch],
                                                              acc[rg][ch], 0, 0, 0);
  }
}

// fc tile: x(f32)@fcW[type]+fcB -> gh bf16. Mixed-type tiles loop types.
__device__ void fc_tile(const MegaParams& p, int tile, int t, char* smem) {
  __syncthreads();  // drain prior smem users (tile loop / earlier phase)
  char* xs = smem;
  char* wtl = smem + 32768;
  const int nbase = tile * NPB;
  const int nend = min(nbase + NPB, p.n);
  const int t0 = p.ntype[nbase];
  const int t1 = p.ntype[nend - 1];  // sorted types

  {
    int row = t >> 1;
    int h = (t & 1) * 64;
    int node = nbase + row;
    int byte0 = row * 256 + h * 2;
    if (node < p.n) {
      const float4* src = (const float4*)(p.x + (size_t)node * 128 + h);
#pragma unroll
      for (int j = 0; j < 8; ++j) {
        float4 a4 = src[j * 2], b4 = src[j * 2 + 1];
        u16 tmp[8] = {f2bf(a4.x), f2bf(a4.y), f2bf(a4.z), f2bf(a4.w),
                      f2bf(b4.x), f2bf(b4.y), f2bf(b4.z), f2bf(b4.w)};
        *(short8*)(xs + SWZ(row, byte0 + j * 16)) = *(short8*)tmp;
      }
    } else {
      short8 z = (short8){0, 0, 0, 0, 0, 0, 0, 0};
#pragma unroll
      for (int j = 0; j < 8; ++j)
        *(short8*)(xs + SWZ(row, byte0 + j * 16)) = z;
    }
  }

  const int lane = t & 63, w = t >> 6;
  const int lr = lane & 15, lk = lane >> 4;

  for (int tt = t0; tt <= t1; ++tt) {
    __syncthreads();  // x staged / prior wt reads done
    stage_tile_bf16(wtl, p.wt + ((size_t)tt << 14), 128, t);
    __syncthreads();

    f32x4 acc[8][2];
#pragma unroll
    for (int rg = 0; rg < 8; ++rg)
#pragma unroll
      for (int ch = 0; ch < 2; ++ch) acc[rg][ch] = (f32x4){0.f, 0.f, 0.f, 0.f};
    mfma_core128(xs, wtl, t, acc);

    float bv0 = p.fcB[tt * 128 + w * 32 + lr];
    float bv1 = p.fcB[tt * 128 + w * 32 + 16 + lr];
#pragma unroll
    for (int rg = 0; rg < 8; ++rg) {
#pragma unroll
      for (int reg = 0; reg < 4; ++reg) {
        int node = nbase + rg * 16 + lk * 4 + reg;
        if (node < p.n && p.ntype[node] == tt) {
          p.gh[(size_t)node * 128 + w * 32 + lr]      = f2bf(acc[rg][0][reg] + bv0);
          p.gh[(size_t)node * 128 + w * 32 + 16 + lr] = f2bf(acc[rg][1][reg] + bv1);
        }
      }
    }
  }
}

// gemm tile: (gh @ W) * dis -> xws bf16
__device__ void gemm_tile(const MegaParams& p, const u16* wtg, int tile, int t,
                          char* smem) {
  __syncthreads();
  char* xs = smem;
  char* wtl = smem + 32768;
  const int nbase = tile * NPB;
  stage_tile_bf16(xs, p.gh + (size_t)nbase * 128, min(p.n - nbase, NPB), t);
  stage_tile_bf16(wtl, wtg, 128, t);
  __syncthreads();

  f32x4 acc[8][2];
#pragma unroll
  for (int rg = 0; rg < 8; ++rg)
#pragma unroll
    for (int ch = 0; ch < 2; ++ch) acc[rg][ch] = (f32x4){0.f, 0.f, 0.f, 0.f};
  mfma_core128(xs, wtl, t, acc);

  const int lane = t & 63, w = t >> 6;
  const int lr = lane & 15, lk = lane >> 4;
#pragma unroll
  for (int rg = 0; rg < 8; ++rg) {
#pragma unroll
    for (int reg = 0; reg < 4; ++reg) {
      int node = nbase + rg * 16 + lk * 4 + reg;
      if (node < p.n) {
        float s = p.dis[node];
        p.xws[(size_t)node * 128 + w * 32 + lr]      = f2bf(acc[rg][0][reg] * s);
        p.xws[(size_t)node * 128 + w * 32 + 16 + lr] = f2bf(acc[rg][1][reg] * s);
      }
    }
  }
}

// fused gather + finalize for one node; 1 wave, 4 edges in flight
__device__ __forceinline__ void gather_node(int node, const int* col_ptr,
                                            const int* edge_row, const u16* xws,
                                            const float* dis, const float* bias,
                                            u16* dst, int lane) {
  const int g = lane & 15;
  const int s = lane >> 4;
  float acc[8] = {0.f, 0.f, 0.f, 0.f, 0.f, 0.f, 0.f, 0.f};
  if (s == 0) {  // self loop
    short8 v = *(const short8*)(xws + (size_t)node * 128 + g * 8);
#pragma unroll
    for (int j = 0; j < 8; ++j) acc[j] = bf2f((u16)v[j]);
  }
  const int e0 = col_ptr[node], e1 = col_ptr[node + 1];
  for (int e = e0 + s; e < e1; e += 4) {
    int r = edge_row[e];
    short8 v = *(const short8*)(xws + (size_t)r * 128 + g * 8);
#pragma unroll
    for (int j = 0; j < 8; ++j) acc[j] += bf2f((u16)v[j]);
  }
#pragma unroll
  for (int j = 0; j < 8; ++j) {
    acc[j] += __shfl_xor(acc[j], 16);
    acc[j] += __shfl_xor(acc[j], 32);
  }
  if (s == 0) {
    float ds = dis[node];
    u16 o[8];
#pragma unroll
    for (int j = 0; j < 8; ++j)
      o[j] = f2bf(fmaxf(acc[j] * ds + bias[g * 8 + j], 0.f));
    *(short8*)(dst + g * 8) = *(short8*)o;
  }
}

__global__ __launch_bounds__(256, 2) void k_mega(MegaParams p) {
  __shared__ char smem[65536];
  cg::grid_group grid = cg::this_grid();
  const int t = threadIdx.x;
  const int b = blockIdx.x;
  const int G = gridDim.x;
  const int gt = b * 256 + t;
  const int GT = G * 256;
  const int nb = (p.n + NPB - 1) / NPB;
  const int nscan = (p.n + 255) / 256;

  // ---- P0: wt transpose/cast + zero ecnt ----
  {
    const int wt_total = (p.T + p.L) * 16384;
    for (int i = gt; i < wt_total; i += GT) {
      int m = i >> 14, dk = i & 16383, d = dk >> 7, k = dk & 127;
      const float* src = (m < p.T) ? (p.fcW + ((size_t)m << 14))
                                   : (p.gcnW + ((size_t)(m - p.T) << 14));
      p.wt[i] = f2bf(src[k * 128 + d]);
    }
    for (int i = gt; i < p.n; i += GT) p.ecnt[i] = 0;
  }
  __threadfence(); grid.sync();

  // ---- P1: fc tiles, then degree count ----
  for (int tile = b; tile < nb; tile += G) fc_tile(p, tile, t, smem);
  for (int i = gt; i < p.e; i += GT) atomicAdd(&p.ecnt[p.col[i]], 1);
  __threadfence(); grid.sync();

  // ---- P2: scan1 (per-256-chunk inclusive scan) ----
  for (int chunk = b; chunk < nscan; chunk += G) {
    __syncthreads();
    int* s = (int*)smem;
    int i = chunk * 256 + t;
    int v = (i < p.n) ? p.ecnt[i] : 0;
    s[t] = v; __syncthreads();
    for (int off = 1; off < 256; off <<= 1) {
      int add = (t >= off) ? s[t - off] : 0; __syncthreads();
      s[t] += add; __syncthreads();
    }
    if (i < p.n) p.scanex[i] = s[t] - v;
    if (t == 255) p.partial[chunk] = s[t];
  }
  __threadfence(); grid.sync();

  // ---- P3: scan2 over partials (nscan <= 256) ----
  if (b == 0) {
    __syncthreads();
    int* s = (int*)smem;
    int v = (t < nscan) ? p.partial[t] : 0;
    s[t] = v; __syncthreads();
    for (int off = 1; off < 256; off <<= 1) {
      int add = (t >= off) ? s[t - off] : 0; __syncthreads();
      s[t] += add; __syncthreads();
    }
    if (t < nscan) p.partial[t] = s[t] - v;  // exclusive
  }
  __threadfence(); grid.sync();

  // ---- P4: col_ptr / cursor / dis ----
  for (int i = gt; i < p.n; i += GT) {
    int pos = p.scanex[i] + p.partial[i >> 8];
    p.col_ptr[i] = pos;
    p.cursor[i] = pos;
    p.dis[i] = rsqrtf((float)(p.ecnt[i] + 1));
  }
  if (gt == 0) p.col_ptr[p.n] = p.e;
  __threadfence(); grid.sync();

  // ---- layers ----
  for (int l = 0; l < p.L; ++l) {
    const u16* wl = p.wt + (size_t)(p.T + l) * 16384;
    for (int tile = b; tile < nb; tile += G) gemm_tile(p, wl, tile, t, smem);
    if (l == 0) {  // CSR fill rides with gemm L0 (needs cursor, feeds gather)
      for (int i = gt; i < p.e; i += GT) {
        int c = p.col[i];
        int pos = atomicAdd(&p.cursor[c], 1);
        p.edge_row[pos] = p.row[i];
      }
    }
    __threadfence(); grid.sync();

    const float* bias = p.gcnB + (size_t)l * 128;
    const int lane = t & 63;
    if (l < p.L - 1) {
      const int ngrp = (p.n + 3) / 4;
      for (int grp = b; grp < ngrp; grp += G) {
        int node = grp * 4 + (t >> 6);
        if (node < p.n)
          gather_node(node, p.col_ptr, p.edge_row, p.xws, p.dis, bias,
                      p.gh + (size_t)node * 128, lane);
      }
    } else {
      const int ngrp = (p.b_total + 3) / 4;
      for (int grp = b; grp < ngrp; grp += G) {
        int bb = grp * 4 + (t >> 6);
        if (bb < p.b_total) {
          int node = p.seqs[(size_t)bb * p.slen];
          gather_node(node, p.col_ptr, p.edge_row, p.xws, p.dis, bias,
                      p.gh2 + (size_t)bb * 128, lane);
        }
      }
    }
    __threadfence(); grid.sync();
  }

  // ---- P9: pred ----
  for (int i = gt; i < p.b_total * p.C; i += GT) {
    int bb = i / p.C, c = i - bb * p.C;
    const u16* g = p.gh2 + (size_t)bb * 128;
    float s = p.predB[c];
#pragma unroll 8
    for (int k = 0; k < 128; ++k) s += bf2f(g[k]) * p.predW[k * p.C + c];
    p.out_logits[i] = s;
    if (c == 0) p.out_label[bb] = (float)p.label[p.seqs[(size_t)bb * p.slen]];
  }
}

extern "C" void kernel_launch(void* const* d_in, const int* in_sizes, int n_in,
                              void* d_out, int out_size, void* d_ws, size_t ws_size,
                              hipStream_t stream) {
  const int n = in_sizes[0] / 128;          // 50000
  const int e = in_sizes[3] / 2;            // 600000
  const int T = in_sizes[5] / (128 * 128);  // 4
  const int L = in_sizes[8] / 128;          // 2
  const int C = in_sizes[13];               // 16
  const int slen = 16;
  const int b_total = in_sizes[2] / slen;   // 2048

  char* ws = (char*)d_ws;
  const size_t node_bf = (size_t)n * 128 * sizeof(u16);

  MegaParams p;
  p.x     = (const float*)d_in[0];
  p.label = (const int*)d_in[1];
  p.seqs  = (const int*)d_in[2];
  p.row   = (const int*)d_in[3];
  p.col   = ((const int*)d_in[3]) + e;
  p.ntype = (const int*)d_in[4];
  p.fcW   = (const float*)d_in[5];
  p.fcB   = (const float*)d_in[6];
  p.gcnW  = (const float*)d_in[7];
  p.gcnB  = (const float*)d_in[8];
  p.predW = (const float*)d_in[12];
  p.predB = (const float*)d_in[13];

  p.gh      = (u16*)ws;                 ws += node_bf;
  p.xws     = (u16*)ws;                 ws += node_bf;
  p.gh2     = (u16*)ws;                 ws += (size_t)b_total * 128 * 2;
  p.wt      = (u16*)ws;                 ws += (size_t)(T + L) * 16384 * 2;
  p.dis     = (float*)ws;               ws += (size_t)n * 4;
  p.ecnt    = (int*)ws;                 ws += (size_t)n * 4;
  p.scanex  = (int*)ws;                 ws += (size_t)n * 4;
  p.col_ptr = (int*)ws;                 ws += (size_t)(n + 16) * 4;
  p.cursor  = (int*)ws;                 ws += (size_t)n * 4;
  p.partial = (int*)ws;                 ws += 1024 * 4;
  p.edge_row= (int*)ws;                 ws += (size_t)e * 4;

  p.out_logits = (float*)d_out;
  p.out_label  = p.out_logits + (size_t)b_total * C;

  p.n = n; p.e = e; p.T = T; p.L = L; p.C = C; p.slen = slen; p.b_total = b_total;

  // grid = co-resident capacity (cooperative requirement), capped at 512
  int dev = 0;
  hipGetDevice(&dev);
  int mp = 0;
  hipDeviceGetAttribute(&mp, hipDeviceAttributeMultiprocessorCount, dev);
  if (mp <= 0) mp = 256;
  int perCU = 0;
  hipOccupancyMaxActiveBlocksPerMultiprocessor(&perCU, k_mega, 256, 0);
  if (perCU < 1) perCU = 1;
  long cap = (long)mp * perCU;
  int G = (int)(cap < 512 ? cap : 512);

  void* args[] = { &p };
  hipLaunchCooperativeKernel((void*)k_mega, dim3(G), dim3(256), args, 0, stream);
}

// Round 8
// 248.604 us; speedup vs baseline: 3.3682x; 3.3682x over previous
//
#include <hip/hip_runtime.h>
#include <hip/hip_bf16.h>

// ---------------------------------------------------------------------------
// HINormer forward, bf16+MFMA multi-kernel (R8).
// R7 lesson: monolithic cooperative kernel forced 2 blocks/CU on latency-bound
// phases -> 3.2x regression. Back to per-phase kernels; launch count cut
// 13 -> 9 by piggybacking independent work (degree-count in k_fc, CSR fill in
// gemm0, pred inside gather_ego) -- dependencies satisfied by kernel
// boundaries, not grid syncs.
// ---------------------------------------------------------------------------

typedef __attribute__((ext_vector_type(8))) short short8;   // 8 bf16
typedef __attribute__((ext_vector_type(4))) float f32x4;
typedef unsigned short u16;

__device__ __forceinline__ float bf2f(u16 u) {
  union { float f; unsigned int i; } v; v.i = (unsigned int)u << 16; return v.f;
}
__device__ __forceinline__ u16 f2bf(float f) {
  union { float f; unsigned int i; } v; v.f = f;
  return (u16)((v.i + 0x7FFF + ((v.i >> 16) & 1)) >> 16);
}

#define NPB 128
#define SWZ(row, byte) ((byte) ^ (((row) & 15) << 4))

// ---- P0: weight transpose/cast + ecnt zero ---------------------------------
__global__ void k_prep(const float* __restrict__ fcW, const float* __restrict__ gcnW,
                       u16* __restrict__ wt, int* __restrict__ ecnt,
                       int T, int wt_total, int n) {
  const int gt = blockIdx.x * 256 + threadIdx.x;
  const int GT = gridDim.x * 256;
  for (int i = gt; i < wt_total; i += GT) {
    int m = i >> 14, dk = i & 16383, d = dk >> 7, k = dk & 127;
    const float* src = (m < T) ? (fcW + ((size_t)m << 14)) : (gcnW + ((size_t)(m - T) << 14));
    wt[i] = f2bf(src[k * 128 + d]);
  }
  for (int i = gt; i < n; i += GT) ecnt[i] = 0;
}

// stage a [128 x 128] bf16 tile into swizzled LDS; rows >= rows_valid zeroed.
__device__ __forceinline__ void stage_tile_bf16(char* smem, const u16* __restrict__ gsrc,
                                                int rows_valid, int t) {
  int row = t >> 1;
  int h = (t & 1) * 64;
  int byte0 = row * 256 + h * 2;
  if (row < rows_valid) {
    const u16* src = gsrc + (size_t)row * 128 + h;
#pragma unroll
    for (int j = 0; j < 8; ++j) {
      short8 v = *(const short8*)(src + j * 8);
      *(short8*)(smem + SWZ(row, byte0 + j * 16)) = v;
    }
  } else {
    short8 z = (short8){0, 0, 0, 0, 0, 0, 0, 0};
#pragma unroll
    for (int j = 0; j < 8; ++j)
      *(short8*)(smem + SWZ(row, byte0 + j * 16)) = z;
  }
}

// 4 waves; wave w covers output cols [w*32, w*32+32). B preloaded (32 VGPR).
__device__ __forceinline__ void mfma_core128(const char* xs, const char* wt, int t,
                                             f32x4 acc[8][2]) {
  const int lane = t & 63, w = t >> 6;
  const int lr = lane & 15, lk = lane >> 4;
  short8 bfrag[4][2];
#pragma unroll
  for (int ks = 0; ks < 4; ++ks) {
    int kb = ks * 64 + lk * 16;
#pragma unroll
    for (int ch = 0; ch < 2; ++ch) {
      int row = w * 32 + ch * 16 + lr;
      bfrag[ks][ch] = *(const short8*)(wt + SWZ(row, row * 256 + kb));
    }
  }
#pragma unroll
  for (int ks = 0; ks < 4; ++ks) {
    int kb = ks * 64 + lk * 16;
    short8 a[8];
#pragma unroll
    for (int rg = 0; rg < 8; ++rg) {
      int row = rg * 16 + lr;
      a[rg] = *(const short8*)(xs + SWZ(row, row * 256 + kb));
    }
#pragma unroll
    for (int rg = 0; rg < 8; ++rg)
#pragma unroll
      for (int ch = 0; ch < 2; ++ch)
        acc[rg][ch] = __builtin_amdgcn_mfma_f32_16x16x32_bf16(a[rg], bfrag[ks][ch],
                                                              acc[rg][ch], 0, 0, 0);
  }
}

// ---- k_fc (+ degree count piggyback) ---------------------------------------
__global__ __launch_bounds__(256) void k_fc(const float* __restrict__ x,
                                            const int* __restrict__ node_type,
                                            const u16* __restrict__ wt_fc,
                                            const float* __restrict__ fcB,
                                            u16* __restrict__ gh, int n_nodes,
                                            const int* __restrict__ col,
                                            int* __restrict__ ecnt, int e_edges) {
  __shared__ char smem[65536];
  char* smem_xs = smem;
  char* smem_wt = smem + 32768;
  const int t = threadIdx.x;
  const int nbase = blockIdx.x * NPB;
  const int nend = min(nbase + NPB, n_nodes);
  const int t0 = node_type[nbase];
  const int t1 = node_type[nend - 1];   // sorted types

  {
    int row = t >> 1;
    int h = (t & 1) * 64;
    int node = nbase + row;
    int byte0 = row * 256 + h * 2;
    if (node < n_nodes) {
      const float4* src = (const float4*)(x + (size_t)node * 128 + h);
#pragma unroll
      for (int j = 0; j < 8; ++j) {
        float4 a4 = src[j * 2], b4 = src[j * 2 + 1];
        u16 tmp[8] = {f2bf(a4.x), f2bf(a4.y), f2bf(a4.z), f2bf(a4.w),
                      f2bf(b4.x), f2bf(b4.y), f2bf(b4.z), f2bf(b4.w)};
        *(short8*)(smem_xs + SWZ(row, byte0 + j * 16)) = *(short8*)tmp;
      }
    } else {
      short8 z = (short8){0, 0, 0, 0, 0, 0, 0, 0};
#pragma unroll
      for (int j = 0; j < 8; ++j)
        *(short8*)(smem_xs + SWZ(row, byte0 + j * 16)) = z;
    }
  }

  const int lane = t & 63, w = t >> 6;
  const int lr = lane & 15, lk = lane >> 4;

  for (int tt = t0; tt <= t1; ++tt) {
    if (tt > t0) __syncthreads();
    stage_tile_bf16(smem_wt, wt_fc + ((size_t)tt << 14), 128, t);
    __syncthreads();

    f32x4 acc[8][2];
#pragma unroll
    for (int rg = 0; rg < 8; ++rg)
#pragma unroll
      for (int ch = 0; ch < 2; ++ch) acc[rg][ch] = (f32x4){0.f, 0.f, 0.f, 0.f};
    mfma_core128(smem_xs, smem_wt, t, acc);

    float bv0 = fcB[tt * 128 + w * 32 + lr];
    float bv1 = fcB[tt * 128 + w * 32 + 16 + lr];
#pragma unroll
    for (int rg = 0; rg < 8; ++rg) {
#pragma unroll
      for (int reg = 0; reg < 4; ++reg) {
        int node = nbase + rg * 16 + lk * 4 + reg;
        if (node < n_nodes && node_type[node] == tt) {
          gh[(size_t)node * 128 + w * 32 + lr]      = f2bf(acc[rg][0][reg] + bv0);
          gh[(size_t)node * 128 + w * 32 + 16 + lr] = f2bf(acc[rg][1][reg] + bv1);
        }
      }
    }
  }

  // piggyback: in-degree count (independent of fc; consumed next launch)
  const int gt = blockIdx.x * 256 + t;
  const int GT = gridDim.x * 256;
  for (int i = gt; i < e_edges; i += GT) atomicAdd(&ecnt[col[i]], 1);
}

// ---- k_gemm_scale (+ optional CSR fill piggyback) --------------------------
__global__ __launch_bounds__(256) void k_gemm_scale(const u16* __restrict__ ghin,
                                                    const u16* __restrict__ wtg,
                                                    const float* __restrict__ dis,
                                                    u16* __restrict__ xws, int n_nodes,
                                                    const int* __restrict__ row,
                                                    const int* __restrict__ col,
                                                    int* __restrict__ cursor,
                                                    int* __restrict__ edge_row,
                                                    int e_edges, int do_fill) {
  __shared__ char smem[65536];
  char* smem_xs = smem;
  char* smem_wt = smem + 32768;
  const int t = threadIdx.x;
  const int nbase = blockIdx.x * NPB;

  stage_tile_bf16(smem_xs, ghin + (size_t)nbase * 128, min(n_nodes - nbase, NPB), t);
  stage_tile_bf16(smem_wt, wtg, 128, t);
  __syncthreads();

  f32x4 acc[8][2];
#pragma unroll
  for (int rg = 0; rg < 8; ++rg)
#pragma unroll
    for (int ch = 0; ch < 2; ++ch) acc[rg][ch] = (f32x4){0.f, 0.f, 0.f, 0.f};
  mfma_core128(smem_xs, smem_wt, t, acc);

  const int lane = t & 63, w = t >> 6;
  const int lr = lane & 15, lk = lane >> 4;
#pragma unroll
  for (int rg = 0; rg < 8; ++rg) {
#pragma unroll
    for (int reg = 0; reg < 4; ++reg) {
      int node = nbase + rg * 16 + lk * 4 + reg;
      if (node < n_nodes) {
        float s = dis[node];
        xws[(size_t)node * 128 + w * 32 + lr]      = f2bf(acc[rg][0][reg] * s);
        xws[(size_t)node * 128 + w * 32 + 16 + lr] = f2bf(acc[rg][1][reg] * s);
      }
    }
  }

  if (do_fill) {  // piggyback: CSR fill (needs cursor from scan3; feeds gather)
    const int gt = blockIdx.x * 256 + t;
    const int GT = gridDim.x * 256;
    for (int i = gt; i < e_edges; i += GT) {
      int c = col[i];
      int pos = atomicAdd(&cursor[c], 1);
      edge_row[pos] = row[i];
    }
  }
}

// ---- scans ------------------------------------------------------------------
__global__ __launch_bounds__(256) void k_scan1(const int* __restrict__ ecnt,
                                               int* __restrict__ scanex,
                                               int* __restrict__ partials, int n) {
  __shared__ int s[256];
  const int t = threadIdx.x;
  const int i = blockIdx.x * 256 + t;
  int v = (i < n) ? ecnt[i] : 0;
  s[t] = v;
  __syncthreads();
  for (int off = 1; off < 256; off <<= 1) {
    int add = (t >= off) ? s[t - off] : 0;
    __syncthreads();
    s[t] += add;
    __syncthreads();
  }
  if (i < n) scanex[i] = s[t] - v;
  if (t == 255) partials[blockIdx.x] = s[t];
}

__global__ __launch_bounds__(256) void k_scan2(int* __restrict__ partials, int np) {
  __shared__ int s[256];
  const int t = threadIdx.x;
  int v = (t < np) ? partials[t] : 0;
  s[t] = v;
  __syncthreads();
  for (int off = 1; off < 256; off <<= 1) {
    int add = (t >= off) ? s[t - off] : 0;
    __syncthreads();
    s[t] += add;
    __syncthreads();
  }
  if (t < np) partials[t] = s[t] - v;  // exclusive
}

__global__ void k_scan3(const int* __restrict__ scanex, const int* __restrict__ partials,
                        const int* __restrict__ ecnt, int* __restrict__ col_ptr,
                        int* __restrict__ cursor, float* __restrict__ dis,
                        int n, int e_total) {
  int i = blockIdx.x * 256 + threadIdx.x;
  if (i < n) {
    int p = scanex[i] + partials[i >> 8];
    col_ptr[i] = p;
    cursor[i] = p;
    dis[i] = rsqrtf((float)(ecnt[i] + 1));
  }
  if (i == 0) col_ptr[n] = e_total;
}

// ---- fused gather + finalize ------------------------------------------------
__device__ __forceinline__ void gather_node(int node, const int* __restrict__ col_ptr,
                                            const int* __restrict__ edge_row,
                                            const u16* __restrict__ xws,
                                            const float* __restrict__ dis,
                                            const float* __restrict__ bias,
                                            u16* __restrict__ dst, int lane) {
  const int g = lane & 15;
  const int s = lane >> 4;
  float acc[8] = {0.f, 0.f, 0.f, 0.f, 0.f, 0.f, 0.f, 0.f};
  if (s == 0) {  // self loop
    short8 v = *(const short8*)(xws + (size_t)node * 128 + g * 8);
#pragma unroll
    for (int j = 0; j < 8; ++j) acc[j] = bf2f((u16)v[j]);
  }
  const int e0 = col_ptr[node], e1 = col_ptr[node + 1];
  for (int e = e0 + s; e < e1; e += 4) {
    int r = edge_row[e];
    short8 v = *(const short8*)(xws + (size_t)r * 128 + g * 8);
#pragma unroll
    for (int j = 0; j < 8; ++j) acc[j] += bf2f((u16)v[j]);
  }
#pragma unroll
  for (int j = 0; j < 8; ++j) {
    acc[j] += __shfl_xor(acc[j], 16);
    acc[j] += __shfl_xor(acc[j], 32);
  }
  if (s == 0) {
    float ds = dis[node];
    u16 o[8];
#pragma unroll
    for (int j = 0; j < 8; ++j)
      o[j] = f2bf(fmaxf(acc[j] * ds + bias[g * 8 + j], 0.f));
    *(short8*)(dst + g * 8) = *(short8*)o;
  }
}

__global__ __launch_bounds__(256) void k_gather(const int* __restrict__ col_ptr,
                                                const int* __restrict__ edge_row,
                                                const u16* __restrict__ xws,
                                                const float* __restrict__ dis,
                                                const float* __restrict__ bias,
                                                u16* __restrict__ gh, int n_nodes) {
  const int t = threadIdx.x;
  const int node = blockIdx.x * 4 + (t >> 6);
  if (node >= n_nodes) return;
  gather_node(node, col_ptr, edge_row, xws, dis, bias,
              gh + (size_t)node * 128, t & 63);
}

// ---- last layer: gather only ego nodes, then predict in-kernel -------------
__global__ __launch_bounds__(256) void k_egopred(const int* __restrict__ col_ptr,
                                                 const int* __restrict__ edge_row,
                                                 const u16* __restrict__ xws,
                                                 const float* __restrict__ dis,
                                                 const float* __restrict__ bias,
                                                 const int* __restrict__ seqs,
                                                 const int* __restrict__ label,
                                                 const float* __restrict__ predW,
                                                 const float* __restrict__ predB,
                                                 float* __restrict__ out,
                                                 float* __restrict__ out_label,
                                                 int b_total, int n_classes, int slen) {
  __shared__ u16 buf[4][128];
  const int t = threadIdx.x;
  const int w = t >> 6, lane = t & 63;
  const int b = blockIdx.x * 4 + w;
  int node = -1;
  if (b < b_total) {
    node = seqs[(size_t)b * slen];
    gather_node(node, col_ptr, edge_row, xws, dis, bias, &buf[w][0], lane);
  }
  __syncthreads();
  if (b < b_total) {
    const int c = lane & 15;     // class (n_classes == 16)
    const int q = lane >> 4;     // k-chunk 0..3
    float s = 0.f;
#pragma unroll 8
    for (int k = q * 32; k < q * 32 + 32; ++k)
      s += bf2f(buf[w][k]) * predW[k * n_classes + c];
    s += __shfl_xor(s, 16);
    s += __shfl_xor(s, 32);
    if (q == 0) out[(size_t)b * n_classes + c] = s + predB[c];
    if (lane == 0) out_label[b] = (float)label[node];
  }
}

extern "C" void kernel_launch(void* const* d_in, const int* in_sizes, int n_in,
                              void* d_out, int out_size, void* d_ws, size_t ws_size,
                              hipStream_t stream) {
  const float* x     = (const float*)d_in[0];
  const int*   label = (const int*)d_in[1];
  const int*   seqs  = (const int*)d_in[2];
  const int*   edge  = (const int*)d_in[3];
  const int*   ntype = (const int*)d_in[4];
  const float* fcW   = (const float*)d_in[5];
  const float* fcB   = (const float*)d_in[6];
  const float* gcnW  = (const float*)d_in[7];
  const float* gcnB  = (const float*)d_in[8];
  const float* predW = (const float*)d_in[12];
  const float* predB = (const float*)d_in[13];

  const int n = in_sizes[0] / 128;          // 50000
  const int e = in_sizes[3] / 2;            // 600000
  const int T = in_sizes[5] / (128 * 128);  // 4
  const int L = in_sizes[8] / 128;          // 2
  const int C = in_sizes[13];               // 16
  const int slen = 16;
  const int b_total = in_sizes[2] / slen;   // 2048

  const int* row = edge;
  const int* col = edge + e;

  char* ws = (char*)d_ws;
  const size_t node_bf = (size_t)n * 128 * sizeof(u16);
  u16*   gh      = (u16*)ws;                 ws += node_bf;
  u16*   xws     = (u16*)ws;                 ws += node_bf;
  u16*   wt      = (u16*)ws;                 ws += (size_t)(T + L) * 16384 * 2;
  float* dis     = (float*)ws;               ws += (size_t)n * 4;
  int*   ecnt    = (int*)ws;                 ws += (size_t)n * 4;
  int*   scanex  = (int*)ws;                 ws += (size_t)n * 4;
  int*   col_ptr = (int*)ws;                 ws += (size_t)(n + 16) * 4;
  int*   cursor  = (int*)ws;                 ws += (size_t)n * 4;
  int*   partial = (int*)ws;                 ws += 1024 * 4;
  int*   edge_row= (int*)ws;                 ws += (size_t)e * 4;

  float* out_logits = (float*)d_out;
  float* out_label  = out_logits + (size_t)b_total * C;

  const int nb = (n + NPB - 1) / NPB;       // 391
  const int nscan = (n + 255) / 256;        // 196
  const int wt_total = (T + L) * 16384;

  hipLaunchKernelGGL(k_prep, dim3(384), dim3(256), 0, stream,
                     fcW, gcnW, wt, ecnt, T, wt_total, n);
  hipLaunchKernelGGL(k_fc, dim3(nb), dim3(256), 0, stream,
                     x, ntype, wt, fcB, gh, n, col, ecnt, e);
  hipLaunchKernelGGL(k_scan1, dim3(nscan), dim3(256), 0, stream, ecnt, scanex, partial, n);
  hipLaunchKernelGGL(k_scan2, dim3(1), dim3(256), 0, stream, partial, nscan);
  hipLaunchKernelGGL(k_scan3, dim3(nscan), dim3(256), 0, stream, scanex, partial, ecnt,
                     col_ptr, cursor, dis, n, e);

  for (int l = 0; l < L; ++l) {
    hipLaunchKernelGGL(k_gemm_scale, dim3(nb), dim3(256), 0, stream,
                       gh, wt + (size_t)(T + l) * 16384, dis, xws, n,
                       row, col, cursor, edge_row, e, (l == 0) ? 1 : 0);
    if (l < L - 1) {
      hipLaunchKernelGGL(k_gather, dim3((n + 3) / 4), dim3(256), 0, stream,
                         col_ptr, edge_row, xws, dis, gcnB + (size_t)l * 128, gh, n);
    } else {
      hipLaunchKernelGGL(k_egopred, dim3((b_total + 3) / 4), dim3(256), 0, stream,
                         col_ptr, edge_row, xws, dis, gcnB + (size_t)l * 128,
                         seqs, label, predW, predB, out_logits, out_label,
                         b_total, C, slen);
    }
  }
}